// Round 12
// baseline (106.550 us; speedup 1.0000x reference)
//
#include <hip/hip_runtime.h>
#include <math.h>

#define B_ 64
#define Q_ 900
#define C_ 256
#define T_ 100
#define N_ 100            // min(Q,T)
#define BIGF 1.0e30f
#define ROWS_PER_LANE 15  // ceil(900/64)
#define CHUNKS 15         // ceil(900/64) row-chunks
#define CWAVES 8          // waves per cost-kernel block

typedef unsigned int u32;
typedef unsigned long long ull;

// ---------------------------------------------------------------------------
// Key scheme (all reductions on INVERTED keys, max semantics, identity 0):
//   key  = ordf(v)<<18 | stale<<17 | row<<7 | t      (50 bits)
//   ikey = ~key
// Fresh winner == exact jnp.argmin flat order (value, q, t).
// ---------------------------------------------------------------------------
__device__ inline u32 hm_ordf(float v) {
    u32 u = __float_as_uint(v);
    return (u & 0x80000000u) ? ~u : (u | 0x80000000u);
}
__device__ inline ull hm_ikey(float v, int r, int t) {
    return ~(((ull)hm_ordf(v) << 18) | ((ull)(u32)r << 7) | (ull)(u32)t);
}

// ---------------------------------------------------------------------------
// Fused cost + column TOP-2 partials. Per-row math byte-for-byte identical to
// rounds 1-11 (same lane mapping, same __shfl_xor trees, same f64 expression
// order -> bit-identical cost matrix). Structural change only: 8 waves/block
// (was 4), each wave owns 8 rows of the 64-row chunk -> 7680 waves (94% of
// device capacity, was 47% cap / 25% measured) to hide the per-row butterfly
// + f64-exp latency chain.
// ---------------------------------------------------------------------------
__global__ __launch_bounds__(512) void hm_cost_colmin(
    const float* __restrict__ logits,   // [B,Q,C]
    const float* __restrict__ pboxes,   // [B,Q,4] cxcywh
    const int*   __restrict__ tlabels,  // [B,T]
    const float* __restrict__ tboxes,   // [B,T,4] cxcywh
    float* __restrict__ cost,           // [B,Q,T]
    ull* __restrict__ part)             // [B,CHUNKS,T,2] inverted top-2 keys
{
    int bc   = blockIdx.x;
    int b    = bc / CHUNKS;
    int c    = bc % CHUNKS;
    int lane = threadIdx.x & 63;
    int wid  = threadIdx.x >> 6;        // 0..7
    int r0   = c * 64;
    int R    = Q_ - r0; if (R > 64) R = 64;

    __shared__ double s_exp[CWAVES][C_];      // 16 KB
    __shared__ ull    s_part[CWAVES][128][2]; // 16 KB

    int ta = lane, tb = 64 + lane;
    bool hb = (tb < T_);
    int laba = tlabels[b * T_ + ta];
    int labb = hb ? tlabels[b * T_ + tb] : 0;
    const float* tba = tboxes + ((size_t)b * T_ + ta) * 4;
    const float* tbb = tboxes + ((size_t)b * T_ + (hb ? tb : 0)) * 4;
    double tcxa = tba[0], tcya = tba[1], twa = tba[2], tha = tba[3];
    double tcxb = tbb[0], tcyb = tbb[1], twb = tbb[2], thb_ = tbb[3];
    double txa1 = tcxa - 0.5 * twa, tya1 = tcya - 0.5 * tha;
    double txa2 = tcxa + 0.5 * twa, tya2 = tcya + 0.5 * tha;
    double txb1 = tcxb - 0.5 * twb, tyb1 = tcyb - 0.5 * thb_;
    double txb2 = tcxb + 0.5 * twb, tyb2 = tcyb + 0.5 * thb_;
    double area2a = fmax(txa2 - txa1, 0.0) * fmax(tya2 - tya1, 0.0);
    double area2b = fmax(txb2 - txb1, 0.0) * fmax(tyb2 - tyb1, 0.0);

    ull ka1 = 0ull, ka2 = 0ull;         // inverted top-2, column ta
    ull kb1 = 0ull, kb2 = 0ull;         // inverted top-2, column tb

    for (int r = r0 + wid; r < r0 + R; r += CWAVES) {
        int bq = b * Q_ + r;

        const float* row = logits + (size_t)bq * C_;
        float v[4];
        float m = -INFINITY;
#pragma unroll
        for (int i = 0; i < 4; ++i) {
            v[i] = row[lane + 64 * i];
            m = fmaxf(m, v[i]);
        }
#pragma unroll
        for (int off = 32; off >= 1; off >>= 1)
            m = fmaxf(m, __shfl_xor(m, off, 64));

        double e[4];
        double s = 0.0;
#pragma unroll
        for (int i = 0; i < 4; ++i) {
            e[i] = exp((double)v[i] - (double)m);
            s += e[i];
        }
#pragma unroll
        for (int off = 32; off >= 1; off >>= 1)
            s += __shfl_xor(s, off, 64);

#pragma unroll
        for (int i = 0; i < 4; ++i)
            s_exp[wid][lane + 64 * i] = e[i];

        const float* pb = pboxes + (size_t)bq * 4;
        double pcx = pb[0], pcy = pb[1], pw = pb[2], ph = pb[3];
        double px1 = pcx - 0.5 * pw, py1 = pcy - 0.5 * ph;
        double px2 = pcx + 0.5 * pw, py2 = pcy + 0.5 * ph;
        double area1 = fmax(px2 - px1, 0.0) * fmax(py2 - py1, 0.0);

        {
            double prob = s_exp[wid][laba] / s;
            double l1 = fabs(pcx - tcxa) + fabs(pcy - tcya) + fabs(pw - twa) + fabs(ph - tha);
            double iw = fmax(fmin(px2, txa2) - fmax(px1, txa1), 0.0);
            double ih = fmax(fmin(py2, tya2) - fmax(py1, tya1), 0.0);
            double inter = iw * ih;
            double uni = area1 + area2a - inter;
            double iou = inter / fmax(uni, 1e-6);
            double ew = fmax(fmax(px2, txa2) - fmin(px1, txa1), 0.0);
            double eh = fmax(fmax(py2, tya2) - fmin(py1, tya1), 0.0);
            double earea = ew * eh;
            double giou = iou - (earea - uni) / fmax(earea, 1e-6);
            double cst = -prob + 5.0 * l1 - 2.0 * giou;
            float cf = (float)cst;
            cost[(size_t)bq * T_ + ta] = cf;
            ull kk = hm_ikey(cf, r, ta);
            if (kk > ka1) { ka2 = ka1; ka1 = kk; }
            else if (kk > ka2) ka2 = kk;
        }
        if (hb) {
            double prob = s_exp[wid][labb] / s;
            double l1 = fabs(pcx - tcxb) + fabs(pcy - tcyb) + fabs(pw - twb) + fabs(ph - thb_);
            double iw = fmax(fmin(px2, txb2) - fmax(px1, txb1), 0.0);
            double ih = fmax(fmin(py2, tyb2) - fmax(py1, tyb1), 0.0);
            double inter = iw * ih;
            double uni = area1 + area2b - inter;
            double iou = inter / fmax(uni, 1e-6);
            double ew = fmax(fmax(px2, txb2) - fmin(px1, txb1), 0.0);
            double eh = fmax(fmax(py2, tyb2) - fmin(py1, tyb1), 0.0);
            double earea = ew * eh;
            double giou = iou - (earea - uni) / fmax(earea, 1e-6);
            double cst = -prob + 5.0 * l1 - 2.0 * giou;
            float cf = (float)cst;
            cost[(size_t)bq * T_ + tb] = cf;
            ull kk = hm_ikey(cf, r, tb);
            if (kk > kb1) { kb2 = kb1; kb1 = kk; }
            else if (kk > kb2) kb2 = kk;
        }
    }

    s_part[wid][lane][0]      = ka1;
    s_part[wid][lane][1]      = ka2;
    s_part[wid][64 + lane][0] = kb1;
    s_part[wid][64 + lane][1] = kb2;
    __syncthreads();
    int tid = threadIdx.x;
    if (tid < T_) {
        ull b1 = 0ull, b2 = 0ull;
#pragma unroll
        for (int w = 0; w < CWAVES; ++w) {
#pragma unroll
            for (int j = 0; j < 2; ++j) {
                ull cc = s_part[w][tid][j];
                if (cc > b1) { b2 = b1; b1 = cc; }
                else if (cc > b2) b2 = cc;
            }
        }
        ull* dst = part + (((size_t)b * CHUNKS + c) * T_ + tid) * 2;
        dst[0] = b1;
        dst[1] = b2;
    }
}

// ---------------------------------------------------------------------------
// u64 DPP helpers (ctrl must be a literal -> template parameter).
// ---------------------------------------------------------------------------
template <int CTRL>
__device__ inline ull hm_dpp64(ull x) {
    u32 lo = (u32)x, hi = (u32)(x >> 32);
    lo = (u32)__builtin_amdgcn_update_dpp(0, (int)lo, CTRL, 0xF, 0xF, false);
    hi = (u32)__builtin_amdgcn_update_dpp(0, (int)hi, CTRL, 0xF, 0xF, false);
    return ((ull)hi << 32) | lo;
}

__device__ inline ull hm_wave_max_chain(ull x) {
    ull p;
    p = hm_dpp64<0x111>(x); x = (p > x) ? p : x;   // row_shr:1
    p = hm_dpp64<0x112>(x); x = (p > x) ? p : x;   // row_shr:2
    p = hm_dpp64<0x114>(x); x = (p > x) ? p : x;   // row_shr:4
    p = hm_dpp64<0x118>(x); x = (p > x) ? p : x;   // row_shr:8
    p = hm_dpp64<0x142>(x); x = (p > x) ? p : x;   // row_bcast:15
    p = hm_dpp64<0x143>(x); x = (p > x) ? p : x;   // row_bcast:31
    return x;                                      // lane 63 holds the result
}

__device__ inline u32 hm_wave_max_lo(ull x) {
    x = hm_wave_max_chain(x);
    return (u32)__builtin_amdgcn_readlane((int)(u32)x, 63);
}
__device__ inline ull hm_wave_max_full(ull x) {
    x = hm_wave_max_chain(x);
    u32 lo = (u32)__builtin_amdgcn_readlane((int)(u32)x, 63);
    u32 hi = (u32)__builtin_amdgcn_readlane((int)(u32)(x >> 32), 63);
    return ((ull)hi << 32) | lo;
}

// ---------------------------------------------------------------------------
// Greedy (UNCHANGED from R11): ONE WAVE per batch, per-column TOP-2 keys,
// in-register promotion on row death, lazy stale-bit rescan (~1/batch).
// ---------------------------------------------------------------------------
__global__ __launch_bounds__(64) void hm_greedy_top2k(
    const float* __restrict__ cost,     // [B,Q,T]
    const ull* __restrict__ part,       // [B,CHUNKS,T,2]
    float* __restrict__ out_src,        // [B,N]
    float* __restrict__ out_tgt)        // [B,N]
{
    int b = blockIdx.x;
    int l = threadIdx.x;                // 0..63
    const float* Cb = cost + (size_t)b * Q_ * T_;

    int  t0 = l, t1 = 64 + l;
    bool a1 = (t1 < T_);

    // ---- phase 0: fold chunk top-2 partials into column top-2 ----
    ull c1a = 0ull, c2a = 0ull, c1b = 0ull, c2b = 0ull;
#pragma unroll
    for (int c = 0; c < CHUNKS; ++c) {
        const ull* p0 = part + (((size_t)b * CHUNKS + c) * T_ + t0) * 2;
#pragma unroll
        for (int j = 0; j < 2; ++j) {
            ull cc = p0[j];
            if (cc > c1a) { c2a = c1a; c1a = cc; }
            else if (cc > c2a) c2a = cc;
        }
        if (a1) {
            const ull* p1 = part + (((size_t)b * CHUNKS + c) * T_ + t1) * 2;
#pragma unroll
            for (int j = 0; j < 2; ++j) {
                ull cc = p1[j];
                if (cc > c1b) { c2b = c1b; c1b = cc; }
                else if (cc > c2b) c2b = cc;
            }
        }
    }

    unsigned removed = 0u;              // bit i => row (l + 64*i) removed
    float* os = out_src + b * N_;
    float* ot = out_tgt + b * N_;

    int k = 0;
    while (k < N_) {
        ull cmax = (c1a > c1b) ? c1a : c1b;
        u32 winlo = hm_wave_max_lo(cmax);
        u32 keylo = ~winlo;
        int t = (int)(keylo & 127u);
        int q = (int)((keylo >> 7) & 1023u);

        if ((keylo >> 17) & 1u) {
            // RARE: stale lower-bound won -> rescan column t, retry k
            ull b1 = 0ull, b2 = 0ull;
#pragma unroll
            for (int i = 0; i < ROWS_PER_LANE; ++i) {
                int r = l + 64 * i;
                bool ok = (r < Q_) && !((removed >> i) & 1u);
                float v = ok ? Cb[(size_t)r * T_ + t] : BIGF;
                ull ik = ok ? hm_ikey(v, r, t) : 0ull;
                if (ik > b1) { b2 = b1; b1 = ik; }
                else if (ik > b2) b2 = ik;
            }
            ull w1 = hm_wave_max_full(b1);
            ull alt = (b1 == w1) ? b2 : b1;   // keys unique
            ull w2 = hm_wave_max_full(alt);
            if (t0 == t) { c1a = w1; c2a = w2; }
            if (t1 == t) { c1b = w1; c2b = w2; }
            continue;
        }

        if (l == 0) { os[k] = (float)q; ot[k] = (float)t; }
        if ((q & 63) == l) removed |= 1u << (q >> 6);

        {
            u32 r1 = ((~(u32)c1a) >> 7) & 1023u;
            u32 r2 = ((~(u32)c2a) >> 7) & 1023u;
            bool die1 = (r1 == (u32)q);
            bool die2 = (r2 == (u32)q);
            ull st2 = c2a & ~(1ull << 17);        // mark stale (lower bound)
            ull nc1 = die1 ? c2a : c1a;
            ull nc2 = (die1 || die2) ? st2 : c2a;
            bool kill = (t0 == t);
            c1a = kill ? 0ull : nc1;
            c2a = kill ? 0ull : nc2;
        }
        {
            u32 r1 = ((~(u32)c1b) >> 7) & 1023u;
            u32 r2 = ((~(u32)c2b) >> 7) & 1023u;
            bool die1 = (r1 == (u32)q);
            bool die2 = (r2 == (u32)q);
            ull st2 = c2b & ~(1ull << 17);
            ull nc1 = die1 ? c2b : c1b;
            ull nc2 = (die1 || die2) ? st2 : c2b;
            bool kill = (t1 == t);
            c1b = kill ? 0ull : nc1;
            c2b = kill ? 0ull : nc2;
        }

        ++k;
    }
}

// ---------------------------------------------------------------------------
extern "C" void kernel_launch(void* const* d_in, const int* in_sizes, int n_in,
                              void* d_out, int out_size, void* d_ws, size_t ws_size,
                              hipStream_t stream)
{
    const float* pred_logits = (const float*)d_in[0];  // [B,Q,C]
    const float* pred_boxes  = (const float*)d_in[1];  // [B,Q,4]
    const int*   tgt_labels  = (const int*)d_in[2];    // [B,T]
    const float* tgt_boxes   = (const float*)d_in[3];  // [B,T,4]

    float* out_cost = (float*)d_out;                       // [B,Q,T]
    float* out_src  = out_cost + (size_t)B_ * Q_ * T_;     // [B,N]
    float* out_tgt  = out_src  + (size_t)B_ * N_;          // [B,N]

    ull* part = (ull*)d_ws;                                // [B,CHUNKS,T,2] 1.54 MB

    // 1: fused softmax + cost + column top-2 partials (8 waves/block)
    hm_cost_colmin<<<B_ * CHUNKS, 512, 0, stream>>>(pred_logits, pred_boxes,
                                                    tgt_labels, tgt_boxes,
                                                    out_cost, part);

    // 2: greedy — one wave per batch, top-2 keys + lazy stale-bit rescan
    hm_greedy_top2k<<<B_, 64, 0, stream>>>(out_cost, part, out_src, out_tgt);
}

// Round 13
// 103.232 us; speedup vs baseline: 1.0321x; 1.0321x over previous
//
#include <hip/hip_runtime.h>
#include <math.h>

#define B_ 64
#define Q_ 900
#define C_ 256
#define T_ 100
#define N_ 100            // min(Q,T)
#define BIGF 1.0e30f
#define ROWS_PER_LANE 15  // ceil(900/64)
#define CHUNKS 15         // ceil(900/64) row-chunks

typedef unsigned int u32;
typedef unsigned long long ull;

// ---------------------------------------------------------------------------
// Key scheme:
//   u64 key  = ordf(v)<<18 | stale<<17 | row<<7 | t   (partials / rescan)
//   ikey = ~key (max semantics, identity 0)
// Greedy splits this into 32-bit pieces: va = ordf(v), ida = stale<<17|row<<7|t.
// Pick order = lex(value, stale, row, t) == jnp.argmin flat order for fresh.
// ---------------------------------------------------------------------------
__device__ inline u32 hm_ordf(float v) {
    u32 u = __float_as_uint(v);
    return (u & 0x80000000u) ? ~u : (u | 0x80000000u);
}
__device__ inline ull hm_ikey(float v, int r, int t) {
    return ~(((ull)hm_ordf(v) << 18) | ((ull)(u32)r << 7) | (ull)(u32)t);
}

// ---------------------------------------------------------------------------
// Fused cost + column TOP-2 partials (R11 config — 4 waves/block, verbatim
// per-row math: bit-identical cost matrix across all rounds).
// ---------------------------------------------------------------------------
__global__ __launch_bounds__(256) void hm_cost_colmin(
    const float* __restrict__ logits,   // [B,Q,C]
    const float* __restrict__ pboxes,   // [B,Q,4] cxcywh
    const int*   __restrict__ tlabels,  // [B,T]
    const float* __restrict__ tboxes,   // [B,T,4] cxcywh
    float* __restrict__ cost,           // [B,Q,T]
    ull* __restrict__ part)             // [B,CHUNKS,T,2] inverted top-2 keys
{
    int bc   = blockIdx.x;
    int b    = bc / CHUNKS;
    int c    = bc % CHUNKS;
    int lane = threadIdx.x & 63;
    int wid  = threadIdx.x >> 6;        // 0..3
    int r0   = c * 64;
    int R    = Q_ - r0; if (R > 64) R = 64;

    __shared__ double s_exp[4][C_];     // 8 KB
    __shared__ ull    s_part[4][128][2];// 8 KB

    int ta = lane, tb = 64 + lane;
    bool hb = (tb < T_);
    int laba = tlabels[b * T_ + ta];
    int labb = hb ? tlabels[b * T_ + tb] : 0;
    const float* tba = tboxes + ((size_t)b * T_ + ta) * 4;
    const float* tbb = tboxes + ((size_t)b * T_ + (hb ? tb : 0)) * 4;
    double tcxa = tba[0], tcya = tba[1], twa = tba[2], tha = tba[3];
    double tcxb = tbb[0], tcyb = tbb[1], twb = tbb[2], thb_ = tbb[3];
    double txa1 = tcxa - 0.5 * twa, tya1 = tcya - 0.5 * tha;
    double txa2 = tcxa + 0.5 * twa, tya2 = tcya + 0.5 * tha;
    double txb1 = tcxb - 0.5 * twb, tyb1 = tcyb - 0.5 * thb_;
    double txb2 = tcxb + 0.5 * twb, tyb2 = tcyb + 0.5 * thb_;
    double area2a = fmax(txa2 - txa1, 0.0) * fmax(tya2 - tya1, 0.0);
    double area2b = fmax(txb2 - txb1, 0.0) * fmax(tyb2 - tyb1, 0.0);

    ull ka1 = 0ull, ka2 = 0ull;
    ull kb1 = 0ull, kb2 = 0ull;

    for (int r = r0 + wid; r < r0 + R; r += 4) {
        int bq = b * Q_ + r;

        const float* row = logits + (size_t)bq * C_;
        float v[4];
        float m = -INFINITY;
#pragma unroll
        for (int i = 0; i < 4; ++i) {
            v[i] = row[lane + 64 * i];
            m = fmaxf(m, v[i]);
        }
#pragma unroll
        for (int off = 32; off >= 1; off >>= 1)
            m = fmaxf(m, __shfl_xor(m, off, 64));

        double e[4];
        double s = 0.0;
#pragma unroll
        for (int i = 0; i < 4; ++i) {
            e[i] = exp((double)v[i] - (double)m);
            s += e[i];
        }
#pragma unroll
        for (int off = 32; off >= 1; off >>= 1)
            s += __shfl_xor(s, off, 64);

#pragma unroll
        for (int i = 0; i < 4; ++i)
            s_exp[wid][lane + 64 * i] = e[i];

        const float* pb = pboxes + (size_t)bq * 4;
        double pcx = pb[0], pcy = pb[1], pw = pb[2], ph = pb[3];
        double px1 = pcx - 0.5 * pw, py1 = pcy - 0.5 * ph;
        double px2 = pcx + 0.5 * pw, py2 = pcy + 0.5 * ph;
        double area1 = fmax(px2 - px1, 0.0) * fmax(py2 - py1, 0.0);

        {
            double prob = s_exp[wid][laba] / s;
            double l1 = fabs(pcx - tcxa) + fabs(pcy - tcya) + fabs(pw - twa) + fabs(ph - tha);
            double iw = fmax(fmin(px2, txa2) - fmax(px1, txa1), 0.0);
            double ih = fmax(fmin(py2, tya2) - fmax(py1, tya1), 0.0);
            double inter = iw * ih;
            double uni = area1 + area2a - inter;
            double iou = inter / fmax(uni, 1e-6);
            double ew = fmax(fmax(px2, txa2) - fmin(px1, txa1), 0.0);
            double eh = fmax(fmax(py2, tya2) - fmin(py1, tya1), 0.0);
            double earea = ew * eh;
            double giou = iou - (earea - uni) / fmax(earea, 1e-6);
            double cst = -prob + 5.0 * l1 - 2.0 * giou;
            float cf = (float)cst;
            cost[(size_t)bq * T_ + ta] = cf;
            ull kk = hm_ikey(cf, r, ta);
            if (kk > ka1) { ka2 = ka1; ka1 = kk; }
            else if (kk > ka2) ka2 = kk;
        }
        if (hb) {
            double prob = s_exp[wid][labb] / s;
            double l1 = fabs(pcx - tcxb) + fabs(pcy - tcyb) + fabs(pw - twb) + fabs(ph - thb_);
            double iw = fmax(fmin(px2, txb2) - fmax(px1, txb1), 0.0);
            double ih = fmax(fmin(py2, tyb2) - fmax(py1, tyb1), 0.0);
            double inter = iw * ih;
            double uni = area1 + area2b - inter;
            double iou = inter / fmax(uni, 1e-6);
            double ew = fmax(fmax(px2, txb2) - fmin(px1, txb1), 0.0);
            double eh = fmax(fmax(py2, tyb2) - fmin(py1, tyb1), 0.0);
            double earea = ew * eh;
            double giou = iou - (earea - uni) / fmax(earea, 1e-6);
            double cst = -prob + 5.0 * l1 - 2.0 * giou;
            float cf = (float)cst;
            cost[(size_t)bq * T_ + tb] = cf;
            ull kk = hm_ikey(cf, r, tb);
            if (kk > kb1) { kb2 = kb1; kb1 = kk; }
            else if (kk > kb2) kb2 = kk;
        }
    }

    s_part[wid][lane][0]      = ka1;
    s_part[wid][lane][1]      = ka2;
    s_part[wid][64 + lane][0] = kb1;
    s_part[wid][64 + lane][1] = kb2;
    __syncthreads();
    int tid = threadIdx.x;
    if (tid < T_) {
        ull b1 = 0ull, b2 = 0ull;
#pragma unroll
        for (int w = 0; w < 4; ++w) {
#pragma unroll
            for (int j = 0; j < 2; ++j) {
                ull cc = s_part[w][tid][j];
                if (cc > b1) { b2 = b1; b1 = cc; }
                else if (cc > b2) b2 = cc;
            }
        }
        ull* dst = part + (((size_t)b * CHUNKS + c) * T_ + tid) * 2;
        dst[0] = b1;
        dst[1] = b2;
    }
}

// ---------------------------------------------------------------------------
// DPP helpers. 32-bit max chain: 2 instr/stage (update_dpp + v_max_u32),
// vs the u64 chain's ~6 (2 dpp + u64 cmp + 2 cndmask). old=0 is inert
// under max. Result lands in lane 63.
// ---------------------------------------------------------------------------
__device__ inline u32 hm_umax32(u32 a, u32 b) { return a > b ? a : b; }

__device__ inline u32 hm_wave_max_u32_lane63(u32 y) {
    y = hm_umax32(y, (u32)__builtin_amdgcn_update_dpp(0, (int)y, 0x111, 0xF, 0xF, false));
    y = hm_umax32(y, (u32)__builtin_amdgcn_update_dpp(0, (int)y, 0x112, 0xF, 0xF, false));
    y = hm_umax32(y, (u32)__builtin_amdgcn_update_dpp(0, (int)y, 0x114, 0xF, 0xF, false));
    y = hm_umax32(y, (u32)__builtin_amdgcn_update_dpp(0, (int)y, 0x118, 0xF, 0xF, false));
    y = hm_umax32(y, (u32)__builtin_amdgcn_update_dpp(0, (int)y, 0x142, 0xF, 0xF, false));
    y = hm_umax32(y, (u32)__builtin_amdgcn_update_dpp(0, (int)y, 0x143, 0xF, 0xF, false));
    return (u32)__builtin_amdgcn_readlane((int)y, 63);
}

template <int CTRL>
__device__ inline ull hm_dpp64(ull x) {
    u32 lo = (u32)x, hi = (u32)(x >> 32);
    lo = (u32)__builtin_amdgcn_update_dpp(0, (int)lo, CTRL, 0xF, 0xF, false);
    hi = (u32)__builtin_amdgcn_update_dpp(0, (int)hi, CTRL, 0xF, 0xF, false);
    return ((ull)hi << 32) | lo;
}
__device__ inline ull hm_wave_max_full(ull x) {     // rare rescan path only
    ull p;
    p = hm_dpp64<0x111>(x); x = (p > x) ? p : x;
    p = hm_dpp64<0x112>(x); x = (p > x) ? p : x;
    p = hm_dpp64<0x114>(x); x = (p > x) ? p : x;
    p = hm_dpp64<0x118>(x); x = (p > x) ? p : x;
    p = hm_dpp64<0x142>(x); x = (p > x) ? p : x;
    p = hm_dpp64<0x143>(x); x = (p > x) ? p : x;
    u32 lo = (u32)__builtin_amdgcn_readlane((int)(u32)x, 63);
    u32 hi = (u32)__builtin_amdgcn_readlane((int)(u32)(x >> 32), 63);
    return ((ull)hi << 32) | lo;
}

// ---------------------------------------------------------------------------
// Greedy: ONE WAVE per batch, 32-bit split state. Per column entry:
//   v  = ordf(value)  (0xFFFFFFFF = dead)
//   id = stale<<17 | row<<7 | t
// Round: phase1 = 32-bit DPP min over v (via ~max);
//        phase2 = 32-bit DPP min over id among v==winner (ties);
//        decode (stale,q,t) from one SGPR; branch-free top-2 maintenance.
// Stale winner (bit17) -> rescan column (rare, ~1/batch), retry k.
// ---------------------------------------------------------------------------
__global__ __launch_bounds__(64) void hm_greedy_32(
    const float* __restrict__ cost,     // [B,Q,T]
    const ull* __restrict__ part,       // [B,CHUNKS,T,2]
    float* __restrict__ out_src,        // [B,N]
    float* __restrict__ out_tgt)        // [B,N]
{
    int b = blockIdx.x;
    int l = threadIdx.x;                // 0..63
    const float* Cb = cost + (size_t)b * Q_ * T_;

    int  t0 = l, t1 = 64 + l;
    bool a1 = (t1 < T_);

    // ---- phase 0: fold chunk top-2 partials (u64), then split to 32-bit ----
    ull c1a = 0ull, c2a = 0ull, c1b = 0ull, c2b = 0ull;
#pragma unroll
    for (int c = 0; c < CHUNKS; ++c) {
        const ull* p0 = part + (((size_t)b * CHUNKS + c) * T_ + t0) * 2;
#pragma unroll
        for (int j = 0; j < 2; ++j) {
            ull cc = p0[j];
            if (cc > c1a) { c2a = c1a; c1a = cc; }
            else if (cc > c2a) c2a = cc;
        }
        if (a1) {
            const ull* p1 = part + (((size_t)b * CHUNKS + c) * T_ + t1) * 2;
#pragma unroll
            for (int j = 0; j < 2; ++j) {
                ull cc = p1[j];
                if (cc > c1b) { c2b = c1b; c1b = cc; }
                else if (cc > c2b) c2b = cc;
            }
        }
    }
    // split: key = ~ikey; v = key>>18, id = key & 0x3FFFF
    u32 va  = (u32)((~c1a) >> 18), ida  = (u32)(~c1a) & 0x3FFFFu;
    u32 v2a = (u32)((~c2a) >> 18), id2a = (u32)(~c2a) & 0x3FFFFu;
    u32 vb  = a1 ? (u32)((~c1b) >> 18) : 0xFFFFFFFFu;
    u32 idb = a1 ? ((u32)(~c1b) & 0x3FFFFu) : 0x3FFFFu;
    u32 v2b = a1 ? (u32)((~c2b) >> 18) : 0xFFFFFFFFu;
    u32 id2b = a1 ? ((u32)(~c2b) & 0x3FFFFu) : 0x3FFFFu;

    unsigned removed = 0u;              // bit i => row (l + 64*i) removed
    float* os = out_src + b * N_;
    float* ot = out_tgt + b * N_;

    int k = 0;
    while (k < N_) {
        // ---- phase 1: wave-min of value (as max of ~v)
        u32 ya = ~va, yb = ~vb;
        u32 winy = hm_wave_max_u32_lane63(ya > yb ? ya : yb);   // SGPR

        // ---- phase 2: wave-min of id among value-ties (as max of ~id)
        u32 za = (ya == winy) ? ~ida : 0u;
        u32 zb = (yb == winy) ? ~idb : 0u;
        u32 winz = hm_wave_max_u32_lane63(za > zb ? za : zb);   // SGPR
        u32 winid = (~winz) & 0x3FFFFu;

        int t = (int)(winid & 127u);
        int q = (int)((winid >> 7) & 1023u);

        if (winid & 0x20000u) {
            // ---- RARE: stale lower-bound won -> rescan column t, retry k
            ull b1 = 0ull, b2 = 0ull;
#pragma unroll
            for (int i = 0; i < ROWS_PER_LANE; ++i) {
                int r = l + 64 * i;
                bool ok = (r < Q_) && !((removed >> i) & 1u);
                float v = ok ? Cb[(size_t)r * T_ + t] : BIGF;
                ull ik = ok ? hm_ikey(v, r, t) : 0ull;
                if (ik > b1) { b2 = b1; b1 = ik; }
                else if (ik > b2) b2 = ik;
            }
            ull w1 = hm_wave_max_full(b1);
            ull alt = (b1 == w1) ? b2 : b1;   // keys unique
            ull w2 = hm_wave_max_full(alt);
            if (t0 == t) {
                va  = (u32)((~w1) >> 18); ida  = (u32)(~w1) & 0x3FFFFu;
                v2a = (u32)((~w2) >> 18); id2a = (u32)(~w2) & 0x3FFFFu;
            }
            if (t1 == t) {
                vb  = (u32)((~w1) >> 18); idb  = (u32)(~w1) & 0x3FFFFu;
                v2b = (u32)((~w2) >> 18); id2b = (u32)(~w2) & 0x3FFFFu;
            }
            continue;
        }

        // ---- accept pick
        if (l == 0) { os[k] = (float)q; ot[k] = (float)t; }
        if ((q & 63) == l) removed |= 1u << (q >> 6);

        // ---- branch-free top-2 maintenance (all 32-bit), column a
        {
            bool die1 = (((ida  >> 7) & 1023u) == (u32)q);
            bool die2 = (((id2a >> 7) & 1023u) == (u32)q);
            u32 nva  = die1 ? v2a  : va;
            u32 nida = die1 ? id2a : ida;
            u32 nid2 = (die1 || die2) ? (id2a | 0x20000u) : id2a;
            bool kill = (t0 == t);
            va   = kill ? 0xFFFFFFFFu : nva;
            ida  = kill ? 0x3FFFFu    : nida;
            v2a  = kill ? 0xFFFFFFFFu : v2a;
            id2a = kill ? 0x3FFFFu    : nid2;
        }
        // ---- column b
        {
            bool die1 = (((idb  >> 7) & 1023u) == (u32)q);
            bool die2 = (((id2b >> 7) & 1023u) == (u32)q);
            u32 nvb  = die1 ? v2b  : vb;
            u32 nidb = die1 ? id2b : idb;
            u32 nid2 = (die1 || die2) ? (id2b | 0x20000u) : id2b;
            bool kill = (t1 == t);
            vb   = kill ? 0xFFFFFFFFu : nvb;
            idb  = kill ? 0x3FFFFu    : nidb;
            v2b  = kill ? 0xFFFFFFFFu : v2b;
            id2b = kill ? 0x3FFFFu    : nid2;
        }

        ++k;
    }
}

// ---------------------------------------------------------------------------
extern "C" void kernel_launch(void* const* d_in, const int* in_sizes, int n_in,
                              void* d_out, int out_size, void* d_ws, size_t ws_size,
                              hipStream_t stream)
{
    const float* pred_logits = (const float*)d_in[0];  // [B,Q,C]
    const float* pred_boxes  = (const float*)d_in[1];  // [B,Q,4]
    const int*   tgt_labels  = (const int*)d_in[2];    // [B,T]
    const float* tgt_boxes   = (const float*)d_in[3];  // [B,T,4]

    float* out_cost = (float*)d_out;                       // [B,Q,T]
    float* out_src  = out_cost + (size_t)B_ * Q_ * T_;     // [B,N]
    float* out_tgt  = out_src  + (size_t)B_ * N_;          // [B,N]

    ull* part = (ull*)d_ws;                                // [B,CHUNKS,T,2] 1.54 MB

    // 1: fused softmax + cost + column top-2 partials (4 waves/block, R11 cfg)
    hm_cost_colmin<<<B_ * CHUNKS, 256, 0, stream>>>(pred_logits, pred_boxes,
                                                    tgt_labels, tgt_boxes,
                                                    out_cost, part);

    // 2: greedy — one wave per batch, 32-bit two-phase DPP rounds
    hm_greedy_32<<<B_, 64, 0, stream>>>(out_cost, part, out_src, out_tgt);
}